// Round 4
// baseline (212.727 us; speedup 1.0000x reference)
//
#include <hip/hip_runtime.h>
#include <stdint.h>

#define NGT_MAX 128
#define SWPAD (NGT_MAX + 1)
#define CAND_CAP 8192
#define FILT_CAP 16384
#define SUB_CAP 2048

// counters: [0]=cand cnt, [1]=fg total, [2]=bg total, [4]=fg filt, [5]=bg filt,
//           [7]=K2 arrival, [8]=K3 arrival

// ---- threefry2x32 (exact JAX semantics) ----
__host__ __device__ inline void tf2x32(uint32_t k0, uint32_t k1, uint32_t c0, uint32_t c1,
                                       uint32_t& o0, uint32_t& o1) {
  uint32_t ks[3] = {k0, k1, k0 ^ k1 ^ 0x1BD11BDAu};
  uint32_t x0 = c0 + ks[0];
  uint32_t x1 = c1 + ks[1];
  const int rot[2][4] = {{13, 15, 26, 6}, {17, 29, 16, 24}};
#pragma unroll
  for (int i = 0; i < 5; ++i) {
#pragma unroll
    for (int j = 0; j < 4; ++j) {
      x0 += x1;
      int r = rot[i & 1][j];
      x1 = (x1 << r) | (x1 >> (32 - r));
      x1 ^= x0;
    }
    x0 += ks[(i + 1) % 3];
    x1 += ks[(i + 2) % 3] + (uint32_t)(i + 1);
  }
  o0 = x0; o1 = x1;
}

// Partitionable threefry: element i uses block (0,i); draw = o0^o1.
// Selection key = (bits>>9, index) lexicographic (stable argsort tiebreak).
__device__ inline uint64_t sel_key(uint32_t i, uint32_t ka, uint32_t kb) {
  uint32_t o0, o1;
  tf2x32(ka, kb, 0u, i, o0, o1);
  uint32_t bits = o0 ^ o1;
  return ((uint64_t)(bits >> 9) << 32) | (uint64_t)i;
}

__device__ inline uint32_t fmap(float v) {
  uint32_t u = __float_as_uint(v);
  return (u & 0x80000000u) ? ~u : (u | 0x80000000u);
}
__device__ inline float funmap(uint32_t m) {
  return (m & 0x80000000u) ? __uint_as_float(m & 0x7FFFFFFFu) : __uint_as_float(~m);
}

__global__ void k_init(uint32_t* counters, uint32_t* gmaxu) {
  int t = threadIdx.x;
  if (t < 16) counters[t] = 0u;
  if (t < NGT_MAX) gmaxu[t] = 0u;  // < fmap(-1); every column gets real contributions
}

// Single IoU pass: per-anchor labels/targets; per-gt quad maxes via DPP quad_perm
// (no bpermute butterfly), block epilogue reduces 64 quads -> pmax row + global atomicMax.
__global__ void __launch_bounds__(256)
k_main(const float4* __restrict__ anc, const float* __restrict__ img,
       const float4* __restrict__ gt, int N, int R,
       uint32_t* __restrict__ pmax, uint32_t* __restrict__ gmaxu,
       float* __restrict__ LBL, float4* __restrict__ TGT,
       uint32_t* __restrict__ counters) {
  __shared__ float4 sgt[NGT_MAX];
  __shared__ float sarea[NGT_MAX];
  __shared__ float swmax[64 * SWPAD];  // [w*16+q][g], pad 129 -> conflict-light
  __shared__ uint32_t scnt[2];
  const int t = threadIdx.x;
  if (t < 2) scnt[t] = 0u;
  if (t < R) {
    float4 g = gt[t];
    sgt[t] = g;
    {
#pragma clang fp contract(off)
      sarea[t] = (g.z - g.x + 1.0f) * (g.w - g.y + 1.0f);
    }
  }
  __syncthreads();
  const int wid = t >> 6, lane = t & 63;
  const int i = blockIdx.x * 256 + t;  // N multiple of 256
  const float H = img[0], W = img[1];
  float4 a = anc[i];
  bool inside = (a.x >= 0.0f) && (a.y >= 0.0f) && (a.z < W) && (a.w < H);
  float area_a;
  {
#pragma clang fp contract(off)
    area_a = (a.z - a.x + 1.0f) * (a.w - a.y + 1.0f);
  }
  if (!inside) area_a = __uint_as_float(0x7FC00000u);  // NaN-poison: v=NaN, fmax ignores
  float* mySw = &swmax[(wid * 16 + (lane >> 2)) * SWPAD];
  float vmax = -1.0f;
#pragma unroll 4
  for (int g = 0; g < R; ++g) {
    float4 gb = sgt[g];
    float v;
    {
#pragma clang fp contract(off)
      float iw = fminf(a.z, gb.z) - fmaxf(a.x, gb.x) + 1.0f;
      float ih = fminf(a.w, gb.w) - fmaxf(a.y, gb.y) + 1.0f;
      float inter = fmaxf(iw, 0.0f) * fmaxf(ih, 0.0f);
      v = inter / (area_a + sarea[g] - inter);
    }
    vmax = fmaxf(vmax, v);
    // quad max via 2 DPP quad_perm steps (no exec-mask churn, no LDS-pipe shuffles)
    int s1 = __builtin_amdgcn_mov_dpp(__float_as_int(v), 0xB1, 0xF, 0xF, true);
    float v1 = fmaxf(v, __int_as_float(s1));
    int s2 = __builtin_amdgcn_mov_dpp(__float_as_int(v1), 0x4E, 0xF, 0xF, true);
    float v2 = fmaxf(v1, __int_as_float(s2));
    mySw[g] = v2;  // 4 lanes same addr/value: benign 4-way write
  }
  float lbl = -1.0f;
  if (inside) {
    if (vmax < 0.3f) lbl = 0.0f;
    if (vmax >= 0.7f) lbl = 1.0f;
  }
  LBL[i] = lbl;
  unsigned long long bf = __ballot(lbl == 1.0f);
  unsigned long long bb = __ballot(lbl == 0.0f);
  if (lane == 0) {
    atomicAdd(&scnt[0], (uint32_t)__popcll(bf));
    atomicAdd(&scnt[1], (uint32_t)__popcll(bb));
  }
  float4 o = make_float4(0.f, 0.f, 0.f, 0.f);
  if (inside) {
    int idx = (int)vmax;  // faithful astype(int32) of max_ov
    idx = idx < 0 ? 0 : idx;
    idx = idx > R - 1 ? R - 1 : idx;
    float4 gb = sgt[idx];
    {
#pragma clang fp contract(off)
      float aw = a.z - a.x + 1.0f;
      float ah = a.w - a.y + 1.0f;
      float acx = a.x + 0.5f * aw;
      float acy = a.y + 0.5f * ah;
      float gw = gb.z - gb.x + 1.0f;
      float gh = gb.w - gb.y + 1.0f;
      float gcx = gb.x + 0.5f * gw;
      float gcy = gb.y + 0.5f * gh;
      o.x = (gcx - acx) / aw;
      o.y = (gcy - acy) / ah;
      o.z = logf(gw / aw);
      o.w = logf(gh / ah);
    }
  }
  TGT[i] = o;
  __syncthreads();
  if (t < R) {
    float m = -1.0f;
#pragma unroll 8
    for (int k2 = 0; k2 < 64; ++k2) m = fmaxf(m, swmax[k2 * SWPAD + t]);
    uint32_t u = fmap(m);
    pmax[blockIdx.x * R + t] = u;
    atomicMax(&gmaxu[t], u);
  }
  if (t == 0) {
    atomicAdd(&counters[1], scnt[0]);
    atomicAdd(&counters[2], scnt[1]);
  }
}

// Tie-set candidates: per block, tied gt columns = (pmax row == gmax); recompute those
// IoUs bit-exactly. Last finishing block runs keep_at_most(cand, R) inline.
__global__ void __launch_bounds__(256)
k_cand(const float4* __restrict__ anc, const float* __restrict__ img,
       const float4* __restrict__ gt, int N, int R, int NB,
       const uint32_t* __restrict__ pmax, const uint32_t* __restrict__ gmaxu,
       float* __restrict__ LBL, uint64_t* __restrict__ candList,
       uint32_t* __restrict__ counters, uint32_t ka, uint32_t kb) {
  __shared__ int tg[NGT_MAX];
  __shared__ float tgm[NGT_MAX];
  __shared__ uint64_t sub[SUB_CAP];
  __shared__ int tcnt;
  __shared__ int slast;
  const int t = threadIdx.x, b = blockIdx.x;
  if (t == 0) tcnt = 0;
  __syncthreads();
  if (t < R) {
    uint32_t pm = pmax[b * R + t];
    uint32_t gm = gmaxu[t];
    if (pm == gm) { int p = atomicAdd(&tcnt, 1); tg[p] = t; tgm[p] = funmap(gm); }
  }
  __syncthreads();
  const int C0 = tcnt;
  if (C0 > 0) {
    const int i = b * 256 + t;
    const float H = img[0], W = img[1];
    float4 a = anc[i];
    bool inside = (a.x >= 0.0f) && (a.y >= 0.0f) && (a.z < W) && (a.w < H);
    if (inside) {
      float area_a;
      {
#pragma clang fp contract(off)
        area_a = (a.z - a.x + 1.0f) * (a.w - a.y + 1.0f);
      }
      bool cand = false;
      for (int j = 0; j < C0; ++j) {
        float4 gb = gt[tg[j]];
        float v;
        {
#pragma clang fp contract(off)
          float ag = (gb.z - gb.x + 1.0f) * (gb.w - gb.y + 1.0f);
          float iw = fminf(a.z, gb.z) - fmaxf(a.x, gb.x) + 1.0f;
          float ih = fminf(a.w, gb.w) - fmaxf(a.y, gb.y) + 1.0f;
          float inter = fmaxf(iw, 0.0f) * fmaxf(ih, 0.0f);
          v = inter / (area_a + ag - inter);
        }
        cand = cand || (v == tgm[j]);
      }
      if (cand) {
        uint32_t p = atomicAdd(&counters[0], 1u);
        if (p < CAND_CAP)
          __hip_atomic_store((unsigned long long*)&candList[p],
                             (unsigned long long)sel_key((uint32_t)i, ka, kb),
                             __ATOMIC_RELAXED, __HIP_MEMORY_SCOPE_AGENT);
      }
    }
  }
  __syncthreads();  // drains vmcnt: block's stores are globally visible
  if (t == 0) {
    __threadfence();
    uint32_t old = __hip_atomic_fetch_add(&counters[7], 1u, __ATOMIC_ACQ_REL,
                                          __HIP_MEMORY_SCOPE_AGENT);
    slast = (old == (uint32_t)(NB - 1)) ? 1 : 0;
  }
  __syncthreads();
  if (!slast) return;
  // --- last block: keep_at_most(cand, R) ---
  uint32_t C = __hip_atomic_load(&counters[0], __ATOMIC_RELAXED, __HIP_MEMORY_SCOPE_AGENT);
  if (C > SUB_CAP) C = SUB_CAP;
  for (uint32_t s = t; s < C; s += 256)
    sub[s] = __hip_atomic_load((unsigned long long*)&candList[s], __ATOMIC_RELAXED,
                               __HIP_MEMORY_SCOPE_AGENT);
  __syncthreads();
  for (uint32_t s = t; s < C; s += 256) {
    uint64_t key = sub[s];
    bool keep = true;
    if (C > (uint32_t)R) {
      uint32_t rank = 0;
      for (uint32_t j = 0; j < C; ++j) rank += (sub[j] < key) ? 1u : 0u;
      keep = (rank < (uint32_t)R);
    }
    if (keep) {
      uint32_t i2 = (uint32_t)key;
      float old = LBL[i2];
      LBL[i2] = 1.0f;
      if (old != 1.0f) atomicAdd(&counters[1], 1u);
      if (old == 0.0f) atomicSub(&counters[2], 1u);
    }
  }
}

// exact k-smallest among filtered list (all keys < T): 256-bin hist + scan + in-bin rank.
__device__ __forceinline__ void do_select(const uint64_t* list, uint32_t Mf, uint32_t k,
                                          uint32_t T, float* LBL, uint32_t* h,
                                          uint32_t* c0, uint32_t* c1, uint64_t* sub,
                                          uint32_t* scal) {
  const int t = threadIdx.x;
  if (Mf <= k) return;  // uniform
  int bl = (T > 1u) ? (32 - __clz(T - 1u)) : 0;
  int shift = bl > 8 ? bl - 8 : 0;
  h[t] = 0u;
  if (t == 0) { scal[0] = 0u; scal[1] = 0u; scal[2] = 0u; }
  __syncthreads();
  for (uint32_t j = t; j < Mf; j += 256) {
    uint64_t key = __hip_atomic_load((unsigned long long*)&list[j], __ATOMIC_RELAXED,
                                     __HIP_MEMORY_SCOPE_AGENT);
    atomicAdd(&h[((uint32_t)(key >> 32)) >> shift], 1u);
  }
  __syncthreads();
  c0[t] = h[t];
  __syncthreads();
  uint32_t* s = c0;
  uint32_t* d = c1;
  for (int dd = 1; dd < 256; dd <<= 1) {
    uint32_t v = s[t];
    if (t >= dd) v += s[t - dd];
    d[t] = v;
    __syncthreads();
    uint32_t* tmp = s; s = d; d = tmp;
  }
  uint32_t inc = s[t];
  uint32_t exc = inc - h[t];
  if (exc < k && inc >= k) { scal[1] = (uint32_t)t; scal[2] = k - exc; }
  __syncthreads();
  const uint32_t binb = scal[1], rneed = scal[2];
  for (uint32_t j = t; j < Mf; j += 256) {
    uint64_t key = __hip_atomic_load((unsigned long long*)&list[j], __ATOMIC_RELAXED,
                                     __HIP_MEMORY_SCOPE_AGENT);
    uint32_t bin = ((uint32_t)(key >> 32)) >> shift;
    if (bin > binb) {
      LBL[(uint32_t)key] = -1.0f;
    } else if (bin == binb) {
      uint32_t p = atomicAdd(&scal[0], 1u);
      if (p < SUB_CAP) sub[p] = key;
    }
  }
  __syncthreads();
  uint32_t c = scal[0] < SUB_CAP ? scal[0] : SUB_CAP;
  for (uint32_t s2 = t; s2 < c; s2 += 256) {
    uint64_t key = sub[s2];
    uint32_t rank = 0u;
    for (uint32_t j = 0; j < c; ++j) rank += (sub[j] < key) ? 1u : 0u;
    if (rank >= rneed) LBL[(uint32_t)key] = -1.0f;
  }
  __syncthreads();
}

// Fused gather (fg+bg, PRNG-threshold prefilter) + last-block exact selects.
__global__ void __launch_bounds__(256)
k_gsel(float* __restrict__ LBL, int N, int NB, uint64_t* __restrict__ listF,
       uint64_t* __restrict__ listB, uint32_t* __restrict__ counters,
       uint32_t k2a, uint32_t k2b, uint32_t k3a, uint32_t k3b) {
  __shared__ uint32_t h[256], c0[256], c1[256];
  __shared__ uint64_t sub[SUB_CAP];
  __shared__ uint32_t scal[4];
  __shared__ uint32_t meta[8];  // 0 M1,1 M2,2 kbg,3 Tfg,4 Tbg,5 needF,6 needB
  __shared__ int slast;
  const int t = threadIdx.x, b = blockIdx.x;
  if (t == 0) {
    uint32_t M1 = counters[1], M2 = counters[2];
    uint32_t nfg = M1 < 128u ? M1 : 128u;
    uint32_t kbg = 256u - nfg;
    meta[0] = M1; meta[1] = M2; meta[2] = kbg;
    meta[5] = (M1 > 128u) ? 1u : 0u;
    meta[6] = (M2 > kbg) ? 1u : 0u;
    uint64_t Tf = 0, Tb = 0;
    if (M1 > 128u) {
      Tf = (((uint64_t)(128u * 32u)) << 23) / (uint64_t)M1;
      if (Tf > (1u << 23)) Tf = (1u << 23);
    }
    if (M2 > kbg) {
      Tb = (((uint64_t)(kbg * 32u)) << 23) / (uint64_t)M2;
      if (Tb > (1u << 23)) Tb = (1u << 23);
    }
    meta[3] = (uint32_t)Tf; meta[4] = (uint32_t)Tb;
  }
  __syncthreads();
  const int i = b * 256 + t;
  float lbl = LBL[i];
  if (lbl == 1.0f) {
    if (meta[5]) {
      uint64_t key = sel_key((uint32_t)i, k2a, k2b);
      if ((uint32_t)(key >> 32) >= meta[3]) {
        LBL[i] = -1.0f;  // provably not in the k smallest
      } else {
        uint32_t p = atomicAdd(&counters[4], 1u);
        if (p < FILT_CAP)
          __hip_atomic_store((unsigned long long*)&listF[p], (unsigned long long)key,
                             __ATOMIC_RELAXED, __HIP_MEMORY_SCOPE_AGENT);
      }
    }
  } else if (lbl == 0.0f) {
    if (meta[6]) {
      uint64_t key = sel_key((uint32_t)i, k3a, k3b);
      if ((uint32_t)(key >> 32) >= meta[4]) {
        LBL[i] = -1.0f;
      } else {
        uint32_t p = atomicAdd(&counters[5], 1u);
        if (p < FILT_CAP)
          __hip_atomic_store((unsigned long long*)&listB[p], (unsigned long long)key,
                             __ATOMIC_RELAXED, __HIP_MEMORY_SCOPE_AGENT);
      }
    }
  }
  __syncthreads();
  if (t == 0) {
    __threadfence();
    uint32_t old = __hip_atomic_fetch_add(&counters[8], 1u, __ATOMIC_ACQ_REL,
                                          __HIP_MEMORY_SCOPE_AGENT);
    slast = (old == (uint32_t)(NB - 1)) ? 1 : 0;
  }
  __syncthreads();
  if (!slast) return;
  uint32_t MfF = 0, MfB = 0;
  if (meta[5]) {
    MfF = __hip_atomic_load(&counters[4], __ATOMIC_RELAXED, __HIP_MEMORY_SCOPE_AGENT);
    if (MfF > FILT_CAP) MfF = FILT_CAP;
  }
  if (meta[6]) {
    MfB = __hip_atomic_load(&counters[5], __ATOMIC_RELAXED, __HIP_MEMORY_SCOPE_AGENT);
    if (MfB > FILT_CAP) MfB = FILT_CAP;
  }
  do_select(listF, meta[5] ? MfF : 0u, 128u, meta[3], LBL, h, c0, c1, sub, scal);
  do_select(listB, meta[6] ? MfB : 0u, meta[2], meta[4], LBL, h, c0, c1, sub, scal);
}

extern "C" void kernel_launch(void* const* d_in, const int* in_sizes, int n_in,
                              void* d_out, int out_size, void* d_ws, size_t ws_size,
                              hipStream_t stream) {
  (void)n_in; (void)out_size; (void)ws_size;
  const int N = in_sizes[0] / 4;  // 262144 anchors (multiple of 256)
  const int R = in_sizes[2] / 4;  // 100 gt boxes
  const int NB = N / 256;
  const float4* anc = (const float4*)d_in[0];
  const float* img = (const float*)d_in[1];
  const float4* gtb = (const float4*)d_in[2];
  float* LBL = (float*)d_out;
  float4* TGT = (float4*)((float*)d_out + N);

  uint8_t* ws = (uint8_t*)d_ws;
  uint32_t* counters = (uint32_t*)ws;                  // 16 u32
  uint32_t* gmaxu = (uint32_t*)(ws + 512);             // NGT_MAX u32
  uint32_t* pmax = (uint32_t*)(ws + 2048);             // NB*R u32 (~410 KB)
  size_t off = 2048 + (size_t)NB * R * 4;
  off = (off + 7) & ~(size_t)7;
  uint64_t* candList = (uint64_t*)(ws + off);
  uint64_t* listF = (uint64_t*)(ws + off + CAND_CAP * 8);
  uint64_t* listB = (uint64_t*)(ws + off + CAND_CAP * 8 + FILT_CAP * 8);

  // Partitionable jax.random.split(key(42), 3): key_j = threefry((0,42),(0,j))
  uint32_t k1a, k1b, k2a, k2b, k3a, k3b;
  tf2x32(0u, 42u, 0u, 0u, k1a, k1b);
  tf2x32(0u, 42u, 0u, 1u, k2a, k2b);
  tf2x32(0u, 42u, 0u, 2u, k3a, k3b);

  k_init<<<1, 128, 0, stream>>>(counters, gmaxu);
  k_main<<<NB, 256, 0, stream>>>(anc, img, gtb, N, R, pmax, gmaxu, LBL, TGT, counters);
  k_cand<<<NB, 256, 0, stream>>>(anc, img, gtb, N, R, NB, pmax, gmaxu, LBL, candList,
                                 counters, k1a, k1b);
  k_gsel<<<NB, 256, 0, stream>>>(LBL, N, NB, listF, listB, counters, k2a, k2b, k3a, k3b);
}

// Round 5
// 164.665 us; speedup vs baseline: 1.2919x; 1.2919x over previous
//
#include <hip/hip_runtime.h>
#include <stdint.h>

#define NGT_MAX 128
#define PADW 101          // LDS row stride (odd -> conflict-light)
#define CAND_CAP 8192
#define FILT_CAP 16384
#define SUB_CAP 2048

// counters: [0]=cand cnt, [1]=fg total, [2]=bg total, [4]=fg filt, [5]=bg filt

// ---- threefry2x32 (exact JAX semantics) ----
__host__ __device__ inline void tf2x32(uint32_t k0, uint32_t k1, uint32_t c0, uint32_t c1,
                                       uint32_t& o0, uint32_t& o1) {
  uint32_t ks[3] = {k0, k1, k0 ^ k1 ^ 0x1BD11BDAu};
  uint32_t x0 = c0 + ks[0];
  uint32_t x1 = c1 + ks[1];
  const int rot[2][4] = {{13, 15, 26, 6}, {17, 29, 16, 24}};
#pragma unroll
  for (int i = 0; i < 5; ++i) {
#pragma unroll
    for (int j = 0; j < 4; ++j) {
      x0 += x1;
      int r = rot[i & 1][j];
      x1 = (x1 << r) | (x1 >> (32 - r));
      x1 ^= x0;
    }
    x0 += ks[(i + 1) % 3];
    x1 += ks[(i + 2) % 3] + (uint32_t)(i + 1);
  }
  o0 = x0; o1 = x1;
}

// Partitionable threefry: element i uses block (0,i); draw = o0^o1.
// Selection key = (bits>>9, index) lexicographic (stable argsort tiebreak).
__device__ inline uint64_t sel_key(uint32_t i, uint32_t ka, uint32_t kb) {
  uint32_t o0, o1;
  tf2x32(ka, kb, 0u, i, o0, o1);
  uint32_t bits = o0 ^ o1;
  return ((uint64_t)(bits >> 9) << 32) | (uint64_t)i;
}

__device__ inline uint32_t fmap(float v) {
  uint32_t u = __float_as_uint(v);
  return (u & 0x80000000u) ? ~u : (u | 0x80000000u);
}
__device__ inline float funmap(uint32_t m) {
  return (m & 0x80000000u) ? __uint_as_float(m & 0x7FFFFFFFu) : __uint_as_float(~m);
}

__global__ void k_init(uint32_t* counters, uint32_t* gmaxu) {
  int t = threadIdx.x;
  if (t < 16) counters[t] = 0u;
  if (t < NGT_MAX) gmaxu[t] = 0u;  // < fmap(-1)
}

// Single IoU pass. Per-g: IoU + 2 DPP quad-max steps + 1 register cndmask (zero LDS
// in the hot loop). Epilogue: 25 LDS writes/lane -> [64 quads][g] table -> per-gt
// block max -> pmax row + guarded global atomicMax.
__global__ void __launch_bounds__(256)
k_main(const float4* __restrict__ anc, const float* __restrict__ img,
       const float4* __restrict__ gt, int N, int R,
       uint32_t* __restrict__ pmax, uint32_t* __restrict__ gmaxu,
       float* __restrict__ LBL, float4* __restrict__ TGT,
       uint32_t* __restrict__ counters) {
  __shared__ float4 sgt[NGT_MAX];
  __shared__ float sarea[NGT_MAX];
  __shared__ float sq[64 * PADW];  // [quad][g]
  __shared__ uint32_t scnt[2];
  const int t = threadIdx.x;
  if (t < 2) scnt[t] = 0u;
  if (t < R) {
    float4 g = gt[t];
    sgt[t] = g;
    {
#pragma clang fp contract(off)
      sarea[t] = (g.z - g.x + 1.0f) * (g.w - g.y + 1.0f);
    }
  }
  __syncthreads();
  const int lane = t & 63, lm = t & 3, q = t >> 2;
  const int i = blockIdx.x * 256 + t;  // N multiple of 256
  const float H = img[0], W = img[1];
  float4 a = anc[i];
  bool inside = (a.x >= 0.0f) && (a.y >= 0.0f) && (a.z < W) && (a.w < H);
  float area_a;
  {
#pragma clang fp contract(off)
    area_a = (a.z - a.x + 1.0f) * (a.w - a.y + 1.0f);
  }
  if (!inside) area_a = __uint_as_float(0x7FC00000u);  // NaN-poison; v_max discards NaN
  const bool b1 = (lm == 1), b2 = (lm == 2), b3 = (lm == 3);
  float part[25];  // part[s] = quad max of g = 4s + lm
  float vmax = -1.0f;
#pragma unroll
  for (int s = 0; s < 25; ++s) {
    const int gb0 = 4 * s;
    if (gb0 >= R) break;  // uniform
    float v2q[4];
#pragma unroll
    for (int k = 0; k < 4; ++k) {
      const int g = gb0 + k;
      if (g < R) {
        float4 gb = sgt[g];
        float v;
        {
#pragma clang fp contract(off)
          float iw = fminf(a.z, gb.z) - fmaxf(a.x, gb.x) + 1.0f;
          float ih = fminf(a.w, gb.w) - fmaxf(a.y, gb.y) + 1.0f;
          float inter = fmaxf(iw, 0.0f) * fmaxf(ih, 0.0f);
          v = inter / (area_a + sarea[g] - inter);
        }
        vmax = fmaxf(vmax, v);
        int s1 = __builtin_amdgcn_mov_dpp(__float_as_int(v), 0xB1, 0xF, 0xF, true);
        float v1 = fmaxf(v, __int_as_float(s1));
        int s2 = __builtin_amdgcn_mov_dpp(__float_as_int(v1), 0x4E, 0xF, 0xF, true);
        v2q[k] = fmaxf(v1, __int_as_float(s2));
      } else {
        v2q[k] = -1.0f;
      }
    }
    float p = v2q[0];
    p = b1 ? v2q[1] : p;
    p = b2 ? v2q[2] : p;
    p = b3 ? v2q[3] : p;
    part[s] = p;
  }
  float lbl = -1.0f;
  if (inside) {
    if (vmax < 0.3f) lbl = 0.0f;
    if (vmax >= 0.7f) lbl = 1.0f;
  }
  LBL[i] = lbl;
  unsigned long long bf = __ballot(lbl == 1.0f);
  unsigned long long bb = __ballot(lbl == 0.0f);
  if (lane == 0) {
    atomicAdd(&scnt[0], (uint32_t)__popcll(bf));
    atomicAdd(&scnt[1], (uint32_t)__popcll(bb));
  }
  float4 o = make_float4(0.f, 0.f, 0.f, 0.f);
  if (inside) {
    int idx = (int)vmax;  // faithful astype(int32) of max_ov
    idx = idx < 0 ? 0 : idx;
    idx = idx > R - 1 ? R - 1 : idx;
    float4 gb = sgt[idx];
    {
#pragma clang fp contract(off)
      float aw = a.z - a.x + 1.0f;
      float ah = a.w - a.y + 1.0f;
      float acx = a.x + 0.5f * aw;
      float acy = a.y + 0.5f * ah;
      float gw = gb.z - gb.x + 1.0f;
      float gh = gb.w - gb.y + 1.0f;
      float gcx = gb.x + 0.5f * gw;
      float gcy = gb.y + 0.5f * gh;
      o.x = (gcx - acx) / aw;
      o.y = (gcy - acy) / ah;
      o.z = logf(gw / aw);
      o.w = logf(gh / ah);
    }
  }
  TGT[i] = o;
  // epilogue: spill per-quad partials to LDS, reduce per-gt over 64 quads
#pragma unroll
  for (int s = 0; s < 25; ++s) {
    const int g = 4 * s + lm;
    if (4 * s >= R) break;
    if (g < R) sq[q * PADW + g] = part[s];
  }
  __syncthreads();
  if (t < R) {
    float m = -1.0f;
#pragma unroll 8
    for (int k2 = 0; k2 < 64; ++k2) m = fmaxf(m, sq[k2 * PADW + t]);
    uint32_t u = fmap(m);
    pmax[blockIdx.x * R + t] = u;
    if (u > gmaxu[t]) atomicMax(&gmaxu[t], u);  // stale-high skip is safe (monotone)
  }
  if (t == 0) {
    atomicAdd(&counters[1], scnt[0]);
    atomicAdd(&counters[2], scnt[1]);
  }
}

// Tie-set candidates: tied gt columns of this block = (pmax row == gmax); recompute
// those IoUs bit-exactly. No cross-block sync.
__global__ void __launch_bounds__(256)
k_cand(const float4* __restrict__ anc, const float* __restrict__ img,
       const float4* __restrict__ gt, int N, int R,
       const uint32_t* __restrict__ pmax, const uint32_t* __restrict__ gmaxu,
       uint64_t* __restrict__ candList, uint32_t* __restrict__ counters,
       uint32_t ka, uint32_t kb) {
  __shared__ int tg[NGT_MAX];
  __shared__ float tgm[NGT_MAX];
  __shared__ int tcnt;
  const int t = threadIdx.x, b = blockIdx.x;
  if (t == 0) tcnt = 0;
  __syncthreads();
  if (t < R) {
    uint32_t pm = pmax[b * R + t];
    uint32_t gm = gmaxu[t];
    if (pm == gm) { int p = atomicAdd(&tcnt, 1); tg[p] = t; tgm[p] = funmap(gm); }
  }
  __syncthreads();
  const int C0 = tcnt;
  if (C0 == 0) return;
  const int i = b * 256 + t;
  const float H = img[0], W = img[1];
  float4 a = anc[i];
  bool inside = (a.x >= 0.0f) && (a.y >= 0.0f) && (a.z < W) && (a.w < H);
  if (!inside) return;
  float area_a;
  {
#pragma clang fp contract(off)
    area_a = (a.z - a.x + 1.0f) * (a.w - a.y + 1.0f);
  }
  bool cand = false;
  for (int j = 0; j < C0; ++j) {
    float4 gb = gt[tg[j]];
    float v;
    {
#pragma clang fp contract(off)
      float ag = (gb.z - gb.x + 1.0f) * (gb.w - gb.y + 1.0f);
      float iw = fminf(a.z, gb.z) - fmaxf(a.x, gb.x) + 1.0f;
      float ih = fminf(a.w, gb.w) - fmaxf(a.y, gb.y) + 1.0f;
      float inter = fmaxf(iw, 0.0f) * fmaxf(ih, 0.0f);
      v = inter / (area_a + ag - inter);
    }
    cand = cand || (v == tgm[j]);
  }
  if (cand) {
    uint32_t p = atomicAdd(&counters[0], 1u);
    if (p < CAND_CAP) candList[p] = sel_key((uint32_t)i, ka, kb);
  }
}

// keep_at_most(cand, R): rank-select k smallest; kept -> label 1 (+ fg/bg count fixup).
__global__ void k_cand_select(const uint64_t* __restrict__ candList,
                              uint32_t* __restrict__ counters,
                              float* __restrict__ LBL, int R) {
  __shared__ uint64_t sub[SUB_CAP];
  uint32_t C = counters[0];
  if (C > SUB_CAP) C = SUB_CAP;
  const int t = threadIdx.x;
  for (uint32_t s = t; s < C; s += 256) sub[s] = candList[s];
  __syncthreads();
  for (uint32_t s = t; s < C; s += 256) {
    uint64_t key = sub[s];
    bool keep = true;
    if (C > (uint32_t)R) {
      uint32_t rank = 0;
      for (uint32_t j = 0; j < C; ++j) rank += (sub[j] < key) ? 1u : 0u;
      keep = (rank < (uint32_t)R);
    }
    if (keep) {
      uint32_t i2 = (uint32_t)key;
      float old = LBL[i2];
      LBL[i2] = 1.0f;
      if (old != 1.0f) atomicAdd(&counters[1], 1u);
      if (old == 0.0f) atomicSub(&counters[2], 1u);
    }
  }
}

// Fused fg+bg gather with PRNG-threshold prefilter (keys >= T provably not in the
// k smallest -> LBL=-1 immediately; survivors ~32k expected per class).
__global__ void __launch_bounds__(256)
k_gather(float* __restrict__ LBL, int N, uint64_t* __restrict__ listF,
         uint64_t* __restrict__ listB, uint32_t* __restrict__ counters,
         uint32_t k2a, uint32_t k2b, uint32_t k3a, uint32_t k3b) {
  __shared__ uint32_t meta[8];  // 3 Tfg, 4 Tbg, 5 needF, 6 needB
  const int t = threadIdx.x, b = blockIdx.x;
  if (t == 0) {
    uint32_t M1 = counters[1], M2 = counters[2];
    uint32_t nfg = M1 < 128u ? M1 : 128u;
    uint32_t kbg = 256u - nfg;
    meta[5] = (M1 > 128u) ? 1u : 0u;
    meta[6] = (M2 > kbg) ? 1u : 0u;
    uint64_t Tf = 0, Tb = 0;
    if (M1 > 128u) {
      Tf = (((uint64_t)(128u * 32u)) << 23) / (uint64_t)M1;
      if (Tf > (1u << 23)) Tf = (1u << 23);
    }
    if (M2 > kbg) {
      Tb = (((uint64_t)(kbg * 32u)) << 23) / (uint64_t)M2;
      if (Tb > (1u << 23)) Tb = (1u << 23);
    }
    meta[3] = (uint32_t)Tf; meta[4] = (uint32_t)Tb;
  }
  __syncthreads();
  const int i = b * 256 + t;
  float lbl = LBL[i];
  if (lbl == 1.0f) {
    if (meta[5]) {
      uint64_t key = sel_key((uint32_t)i, k2a, k2b);
      if ((uint32_t)(key >> 32) >= meta[3]) {
        LBL[i] = -1.0f;
      } else {
        uint32_t p = atomicAdd(&counters[4], 1u);
        if (p < FILT_CAP) listF[p] = key;
      }
    }
  } else if (lbl == 0.0f) {
    if (meta[6]) {
      uint64_t key = sel_key((uint32_t)i, k3a, k3b);
      if ((uint32_t)(key >> 32) >= meta[4]) {
        LBL[i] = -1.0f;
      } else {
        uint32_t p = atomicAdd(&counters[5], 1u);
        if (p < FILT_CAP) listB[p] = key;
      }
    }
  }
}

// exact k-smallest among filtered list (all keys < T): 256-bin hist + scan + in-bin rank.
__device__ __forceinline__ void do_select(const uint64_t* list, uint32_t Mf, uint32_t k,
                                          uint32_t T, float* LBL, uint32_t* h,
                                          uint32_t* c0, uint32_t* c1, uint64_t* sub,
                                          uint32_t* scal) {
  const int t = threadIdx.x;
  if (Mf <= k) return;  // keep all (uniform)
  int bl = (T > 1u) ? (32 - __clz(T - 1u)) : 0;
  int shift = bl > 8 ? bl - 8 : 0;
  h[t] = 0u;
  if (t == 0) { scal[0] = 0u; scal[1] = 0u; scal[2] = 0u; }
  __syncthreads();
  for (uint32_t j = t; j < Mf; j += 256)
    atomicAdd(&h[((uint32_t)(list[j] >> 32)) >> shift], 1u);
  __syncthreads();
  c0[t] = h[t];
  __syncthreads();
  uint32_t* s = c0;
  uint32_t* d = c1;
  for (int dd = 1; dd < 256; dd <<= 1) {
    uint32_t v = s[t];
    if (t >= dd) v += s[t - dd];
    d[t] = v;
    __syncthreads();
    uint32_t* tmp = s; s = d; d = tmp;
  }
  uint32_t inc = s[t];
  uint32_t exc = inc - h[t];
  if (exc < k && inc >= k) { scal[1] = (uint32_t)t; scal[2] = k - exc; }
  __syncthreads();
  const uint32_t binb = scal[1], rneed = scal[2];
  for (uint32_t j = t; j < Mf; j += 256) {
    uint64_t key = list[j];
    uint32_t bin = ((uint32_t)(key >> 32)) >> shift;
    if (bin > binb) {
      LBL[(uint32_t)key] = -1.0f;
    } else if (bin == binb) {
      uint32_t p = atomicAdd(&scal[0], 1u);
      if (p < SUB_CAP) sub[p] = key;
    }
  }
  __syncthreads();
  uint32_t c = scal[0] < SUB_CAP ? scal[0] : SUB_CAP;
  for (uint32_t s2 = t; s2 < c; s2 += 256) {
    uint64_t key = sub[s2];
    uint32_t rank = 0u;
    for (uint32_t j = 0; j < c; ++j) rank += (sub[j] < key) ? 1u : 0u;
    if (rank >= rneed) LBL[(uint32_t)key] = -1.0f;
  }
  __syncthreads();
}

__global__ void __launch_bounds__(256)
k_sel(float* __restrict__ LBL, const uint64_t* __restrict__ listF,
      const uint64_t* __restrict__ listB, uint32_t* __restrict__ counters) {
  __shared__ uint32_t h[256], c0[256], c1[256];
  __shared__ uint64_t sub[SUB_CAP];
  __shared__ uint32_t scal[4];
  uint32_t M1 = counters[1], M2 = counters[2];
  uint32_t nfg = M1 < 128u ? M1 : 128u;
  uint32_t kbg = 256u - nfg;
  uint32_t Tf = 0, Tb = 0;
  if (M1 > 128u) {
    uint64_t x = (((uint64_t)(128u * 32u)) << 23) / (uint64_t)M1;
    if (x > (1u << 23)) x = (1u << 23);
    Tf = (uint32_t)x;
  }
  if (M2 > kbg) {
    uint64_t x = (((uint64_t)(kbg * 32u)) << 23) / (uint64_t)M2;
    if (x > (1u << 23)) x = (1u << 23);
    Tb = (uint32_t)x;
  }
  if (M1 > 128u) {
    uint32_t Mf = counters[4];
    if (Mf > FILT_CAP) Mf = FILT_CAP;
    do_select(listF, Mf, 128u, Tf, LBL, h, c0, c1, sub, scal);
  }
  if (M2 > kbg) {
    uint32_t Mf = counters[5];
    if (Mf > FILT_CAP) Mf = FILT_CAP;
    do_select(listB, Mf, kbg, Tb, LBL, h, c0, c1, sub, scal);
  }
}

extern "C" void kernel_launch(void* const* d_in, const int* in_sizes, int n_in,
                              void* d_out, int out_size, void* d_ws, size_t ws_size,
                              hipStream_t stream) {
  (void)n_in; (void)out_size; (void)ws_size;
  const int N = in_sizes[0] / 4;  // 262144 anchors (multiple of 256)
  const int R = in_sizes[2] / 4;  // 100 gt boxes
  const int NB = N / 256;
  const float4* anc = (const float4*)d_in[0];
  const float* img = (const float*)d_in[1];
  const float4* gtb = (const float4*)d_in[2];
  float* LBL = (float*)d_out;
  float4* TGT = (float4*)((float*)d_out + N);

  uint8_t* ws = (uint8_t*)d_ws;
  uint32_t* counters = (uint32_t*)ws;                  // 16 u32
  uint32_t* gmaxu = (uint32_t*)(ws + 512);             // NGT_MAX u32
  uint32_t* pmax = (uint32_t*)(ws + 2048);             // NB*R u32 (~410 KB)
  size_t off = 2048 + (size_t)NB * R * 4;
  off = (off + 7) & ~(size_t)7;
  uint64_t* candList = (uint64_t*)(ws + off);
  uint64_t* listF = (uint64_t*)(ws + off + CAND_CAP * 8);
  uint64_t* listB = (uint64_t*)(ws + off + CAND_CAP * 8 + FILT_CAP * 8);

  // Partitionable jax.random.split(key(42), 3): key_j = threefry((0,42),(0,j))
  uint32_t k1a, k1b, k2a, k2b, k3a, k3b;
  tf2x32(0u, 42u, 0u, 0u, k1a, k1b);
  tf2x32(0u, 42u, 0u, 1u, k2a, k2b);
  tf2x32(0u, 42u, 0u, 2u, k3a, k3b);

  k_init<<<1, 128, 0, stream>>>(counters, gmaxu);
  k_main<<<NB, 256, 0, stream>>>(anc, img, gtb, N, R, pmax, gmaxu, LBL, TGT, counters);
  k_cand<<<NB, 256, 0, stream>>>(anc, img, gtb, N, R, pmax, gmaxu, candList, counters,
                                 k1a, k1b);
  k_cand_select<<<1, 256, 0, stream>>>(candList, counters, LBL, R);
  k_gather<<<NB, 256, 0, stream>>>(LBL, N, listF, listB, counters, k2a, k2b, k3a, k3b);
  k_sel<<<1, 256, 0, stream>>>(LBL, listF, listB, counters);
}

// Round 6
// 142.974 us; speedup vs baseline: 1.4879x; 1.1517x over previous
//
#include <hip/hip_runtime.h>
#include <stdint.h>

#define NGT_MAX 128
#define CAND_CAP 8192
#define FILT_CAP 16384
#define SUB_CAP 2048

// counters: [0]=cand cnt, [1]=fg total M1, [2]=bg total M2, [4]=fg filt, [5]=bg filt,
//           [8]=needF, [9]=needB, [10]=Tf, [11]=Tb, [12]=kbg

// ---- threefry2x32 (exact JAX semantics) ----
__host__ __device__ inline void tf2x32(uint32_t k0, uint32_t k1, uint32_t c0, uint32_t c1,
                                       uint32_t& o0, uint32_t& o1) {
  uint32_t ks[3] = {k0, k1, k0 ^ k1 ^ 0x1BD11BDAu};
  uint32_t x0 = c0 + ks[0];
  uint32_t x1 = c1 + ks[1];
  const int rot[2][4] = {{13, 15, 26, 6}, {17, 29, 16, 24}};
#pragma unroll
  for (int i = 0; i < 5; ++i) {
#pragma unroll
    for (int j = 0; j < 4; ++j) {
      x0 += x1;
      int r = rot[i & 1][j];
      x1 = (x1 << r) | (x1 >> (32 - r));
      x1 ^= x0;
    }
    x0 += ks[(i + 1) % 3];
    x1 += ks[(i + 2) % 3] + (uint32_t)(i + 1);
  }
  o0 = x0; o1 = x1;
}

// Partitionable threefry: element i uses block (0,i); draw = o0^o1.
// Selection key = (bits>>9, index) lexicographic (stable argsort tiebreak).
__device__ inline uint64_t sel_key(uint32_t i, uint32_t ka, uint32_t kb) {
  uint32_t o0, o1;
  tf2x32(ka, kb, 0u, i, o0, o1);
  uint32_t bits = o0 ^ o1;
  return ((uint64_t)(bits >> 9) << 32) | (uint64_t)i;
}

__device__ inline uint32_t fmap(float v) {
  uint32_t u = __float_as_uint(v);
  return (u & 0x80000000u) ? ~u : (u | 0x80000000u);
}
__device__ inline float funmap(uint32_t m) {
  return (m & 0x80000000u) ? __uint_as_float(m & 0x7FFFFFFFu) : __uint_as_float(~m);
}

// Single IoU pass. Per-g: IoU + 2 DPP quad-max steps + register cndmask (zero LDS in
// hot loop). Epilogue: per-gt block max -> pmax row + guarded global atomicMax.
// fg/bg counts -> plain pmeta[b] store (no global atomics).
__global__ void __launch_bounds__(256)
k_main(const float4* __restrict__ anc, const float* __restrict__ img,
       const float4* __restrict__ gt, int N, int R,
       uint32_t* __restrict__ pmax, uint32_t* __restrict__ gmaxu,
       float* __restrict__ LBL, float4* __restrict__ TGT,
       uint32_t* __restrict__ pmeta) {
  __shared__ float4 sgt[NGT_MAX];
  __shared__ float sarea[NGT_MAX];
  __shared__ float sq[64 * 101];  // [quad][g], odd stride
  __shared__ uint32_t scnt[2];
  const int t = threadIdx.x;
  if (t < 2) scnt[t] = 0u;
  if (t < R) {
    float4 g = gt[t];
    sgt[t] = g;
    {
#pragma clang fp contract(off)
      sarea[t] = (g.z - g.x + 1.0f) * (g.w - g.y + 1.0f);
    }
  }
  __syncthreads();
  const int lane = t & 63, lm = t & 3, q = t >> 2;
  const int i = blockIdx.x * 256 + t;  // N multiple of 256
  const float H = img[0], W = img[1];
  float4 a = anc[i];
  bool inside = (a.x >= 0.0f) && (a.y >= 0.0f) && (a.z < W) && (a.w < H);
  float area_a;
  {
#pragma clang fp contract(off)
    area_a = (a.z - a.x + 1.0f) * (a.w - a.y + 1.0f);
  }
  if (!inside) area_a = __uint_as_float(0x7FC00000u);  // NaN-poison; v_max discards NaN
  const bool b1 = (lm == 1), b2 = (lm == 2), b3 = (lm == 3);
  float part[25];
  float vmax = -1.0f;
#pragma unroll
  for (int s = 0; s < 25; ++s) {
    const int gb0 = 4 * s;
    if (gb0 >= R) break;
    float v2q[4];
#pragma unroll
    for (int k = 0; k < 4; ++k) {
      const int g = gb0 + k;
      if (g < R) {
        float4 gb = sgt[g];
        float v;
        {
#pragma clang fp contract(off)
          float iw = fminf(a.z, gb.z) - fmaxf(a.x, gb.x) + 1.0f;
          float ih = fminf(a.w, gb.w) - fmaxf(a.y, gb.y) + 1.0f;
          float inter = fmaxf(iw, 0.0f) * fmaxf(ih, 0.0f);
          v = inter / (area_a + sarea[g] - inter);
        }
        vmax = fmaxf(vmax, v);
        int s1 = __builtin_amdgcn_mov_dpp(__float_as_int(v), 0xB1, 0xF, 0xF, true);
        float v1 = fmaxf(v, __int_as_float(s1));
        int s2 = __builtin_amdgcn_mov_dpp(__float_as_int(v1), 0x4E, 0xF, 0xF, true);
        v2q[k] = fmaxf(v1, __int_as_float(s2));
      } else {
        v2q[k] = -1.0f;
      }
    }
    float p = v2q[0];
    p = b1 ? v2q[1] : p;
    p = b2 ? v2q[2] : p;
    p = b3 ? v2q[3] : p;
    part[s] = p;
  }
  float lbl = -1.0f;
  if (inside) {
    if (vmax < 0.3f) lbl = 0.0f;
    if (vmax >= 0.7f) lbl = 1.0f;
  }
  LBL[i] = lbl;
  unsigned long long bf = __ballot(lbl == 1.0f);
  unsigned long long bb = __ballot(lbl == 0.0f);
  if (lane == 0) {
    atomicAdd(&scnt[0], (uint32_t)__popcll(bf));
    atomicAdd(&scnt[1], (uint32_t)__popcll(bb));
  }
  float4 o = make_float4(0.f, 0.f, 0.f, 0.f);
  if (inside) {
    int idx = (int)vmax;  // faithful astype(int32) of max_ov
    idx = idx < 0 ? 0 : idx;
    idx = idx > R - 1 ? R - 1 : idx;
    float4 gb = sgt[idx];
    {
#pragma clang fp contract(off)
      float aw = a.z - a.x + 1.0f;
      float ah = a.w - a.y + 1.0f;
      float acx = a.x + 0.5f * aw;
      float acy = a.y + 0.5f * ah;
      float gw = gb.z - gb.x + 1.0f;
      float gh = gb.w - gb.y + 1.0f;
      float gcx = gb.x + 0.5f * gw;
      float gcy = gb.y + 0.5f * gh;
      o.x = (gcx - acx) / aw;
      o.y = (gcy - acy) / ah;
      o.z = logf(gw / aw);
      o.w = logf(gh / ah);
    }
  }
  TGT[i] = o;
#pragma unroll
  for (int s = 0; s < 25; ++s) {
    const int g = 4 * s + lm;
    if (4 * s >= R) break;
    if (g < R) sq[q * 101 + g] = part[s];
  }
  __syncthreads();
  if (t < R) {
    float m = -1.0f;
#pragma unroll 8
    for (int k2 = 0; k2 < 64; ++k2) m = fmaxf(m, sq[k2 * 101 + t]);
    uint32_t u = fmap(m);
    pmax[blockIdx.x * R + t] = u;
    if (u > gmaxu[t]) atomicMax(&gmaxu[t], u);  // stale-high skip safe (monotone)
  }
  if (t == 0) pmeta[blockIdx.x] = scnt[0] | (scnt[1] << 16);
}

// Tie-set candidates, block-staged append (1 global atomic per producing block).
__global__ void __launch_bounds__(256)
k_cand(const float4* __restrict__ anc, const float* __restrict__ img,
       const float4* __restrict__ gt, int N, int R,
       const uint32_t* __restrict__ pmax, const uint32_t* __restrict__ gmaxu,
       uint64_t* __restrict__ candList, uint32_t* __restrict__ counters,
       uint32_t ka, uint32_t kb) {
  __shared__ int tg[NGT_MAX];
  __shared__ float tgm[NGT_MAX];
  __shared__ uint64_t buf[256];
  __shared__ uint32_t bcnt, bbase;
  __shared__ int tcnt;
  const int t = threadIdx.x, b = blockIdx.x;
  if (t == 0) { tcnt = 0; bcnt = 0u; }
  __syncthreads();
  if (t < R) {
    uint32_t pm = pmax[b * R + t];
    uint32_t gm = gmaxu[t];
    if (pm == gm) { int p = atomicAdd(&tcnt, 1); tg[p] = t; tgm[p] = funmap(gm); }
  }
  __syncthreads();
  const int C0 = tcnt;
  if (C0 == 0) return;
  const int i = b * 256 + t;
  const float H = img[0], W = img[1];
  float4 a = anc[i];
  bool inside = (a.x >= 0.0f) && (a.y >= 0.0f) && (a.z < W) && (a.w < H);
  if (inside) {
    float area_a;
    {
#pragma clang fp contract(off)
      area_a = (a.z - a.x + 1.0f) * (a.w - a.y + 1.0f);
    }
    bool cand = false;
    for (int j = 0; j < C0; ++j) {
      float4 gb = gt[tg[j]];
      float v;
      {
#pragma clang fp contract(off)
        float ag = (gb.z - gb.x + 1.0f) * (gb.w - gb.y + 1.0f);
        float iw = fminf(a.z, gb.z) - fmaxf(a.x, gb.x) + 1.0f;
        float ih = fminf(a.w, gb.w) - fmaxf(a.y, gb.y) + 1.0f;
        float inter = fmaxf(iw, 0.0f) * fmaxf(ih, 0.0f);
        v = inter / (area_a + ag - inter);
      }
      cand = cand || (v == tgm[j]);
    }
    if (cand) {
      uint32_t p = atomicAdd(&bcnt, 1u);
      buf[p] = sel_key((uint32_t)i, ka, kb);
    }
  }
  __syncthreads();
  if (t == 0 && bcnt) bbase = atomicAdd(&counters[0], bcnt);
  __syncthreads();
  for (uint32_t j = t; j < bcnt; j += 256) {
    uint32_t p = bbase + j;
    if (p < CAND_CAP) candList[p] = buf[j];
  }
}

// Single block: sum pmeta -> base M1/M2; keep_at_most(cand,R) rank-select + LBL flips
// (+ count fixup); publish thresholds/meta for gather+select.
__global__ void __launch_bounds__(256)
k_meta(const uint64_t* __restrict__ candList, uint32_t* __restrict__ counters,
       float* __restrict__ LBL, const uint32_t* __restrict__ pmeta, int NB, int R) {
  __shared__ uint64_t red[256];
  __shared__ int redA[256], redB[256];
  __shared__ uint64_t sub[SUB_CAP];
  const int t = threadIdx.x;
  uint64_t sm = 0;
  for (int j = t; j < NB; j += 256) {
    uint32_t v = pmeta[j];
    sm += (uint64_t)(v & 0xFFFFu) | ((uint64_t)(v >> 16) << 32);
  }
  red[t] = sm;
  __syncthreads();
  for (int s = 128; s > 0; s >>= 1) {
    if (t < s) red[t] += red[t + s];
    __syncthreads();
  }
  const uint32_t baseF = (uint32_t)(red[0] & 0xFFFFFFFFu);
  const uint32_t baseB = (uint32_t)(red[0] >> 32);
  // cand rank-select
  uint32_t C = counters[0];
  if (C > SUB_CAP) C = SUB_CAP;
  for (uint32_t s = t; s < C; s += 256) sub[s] = candList[s];
  __syncthreads();
  int dF = 0, dB = 0;
  for (uint32_t s = t; s < C; s += 256) {
    uint64_t key = sub[s];
    bool keep = true;
    if (C > (uint32_t)R) {
      uint32_t rank = 0;
      for (uint32_t j = 0; j < C; ++j) rank += (sub[j] < key) ? 1u : 0u;
      keep = (rank < (uint32_t)R);
    }
    if (keep) {
      uint32_t i2 = (uint32_t)key;
      float old = LBL[i2];
      LBL[i2] = 1.0f;
      if (old != 1.0f) dF++;
      if (old == 0.0f) dB--;
    }
  }
  redA[t] = dF; redB[t] = dB;
  __syncthreads();
  for (int s = 128; s > 0; s >>= 1) {
    if (t < s) { redA[t] += redA[t + s]; redB[t] += redB[t + s]; }
    __syncthreads();
  }
  if (t == 0) {
    uint32_t M1 = baseF + (uint32_t)redA[0];
    uint32_t M2 = baseB + (uint32_t)(int32_t)redB[0];
    counters[1] = M1; counters[2] = M2;
    uint32_t nfg = M1 < 128u ? M1 : 128u;
    uint32_t kbg = 256u - nfg;
    counters[12] = kbg;
    counters[8] = (M1 > 128u) ? 1u : 0u;
    counters[9] = (M2 > kbg) ? 1u : 0u;
    uint64_t Tf = 0, Tb = 0;
    if (M1 > 128u) {
      Tf = (((uint64_t)(128u * 32u)) << 23) / (uint64_t)M1;
      if (Tf > (1u << 23)) Tf = (1u << 23);
    }
    if (M2 > kbg) {
      Tb = (((uint64_t)(kbg * 32u)) << 23) / (uint64_t)M2;
      if (Tb > (1u << 23)) Tb = (1u << 23);
    }
    counters[10] = (uint32_t)Tf; counters[11] = (uint32_t)Tb;
  }
}

// Fused fg+bg gather with PRNG-threshold prefilter; block-staged appends
// (<=1 global atomic per block per list, coalesced bulk stores).
__global__ void __launch_bounds__(256)
k_gather(float* __restrict__ LBL, int N, uint64_t* __restrict__ listF,
         uint64_t* __restrict__ listB, uint32_t* __restrict__ counters,
         uint32_t k2a, uint32_t k2b, uint32_t k3a, uint32_t k3b) {
  __shared__ uint64_t bufF[256], bufB[256];
  __shared__ uint32_t cF, cB, oF, oB;
  const int t = threadIdx.x, b = blockIdx.x;
  if (t == 0) { cF = 0u; cB = 0u; }
  __syncthreads();
  const uint32_t needF = counters[8], needB = counters[9];
  const uint32_t Tf = counters[10], Tb = counters[11];
  const int i = b * 256 + t;
  float lbl = LBL[i];
  if (lbl == 1.0f) {
    if (needF) {
      uint64_t key = sel_key((uint32_t)i, k2a, k2b);
      if ((uint32_t)(key >> 32) >= Tf) {
        LBL[i] = -1.0f;  // provably not among the k smallest
      } else {
        uint32_t p = atomicAdd(&cF, 1u);
        bufF[p] = key;
      }
    }
  } else if (lbl == 0.0f) {
    if (needB) {
      uint64_t key = sel_key((uint32_t)i, k3a, k3b);
      if ((uint32_t)(key >> 32) >= Tb) {
        LBL[i] = -1.0f;
      } else {
        uint32_t p = atomicAdd(&cB, 1u);
        bufB[p] = key;
      }
    }
  }
  __syncthreads();
  if (t == 0 && cF) oF = atomicAdd(&counters[4], cF);
  if (t == 64 && cB) oB = atomicAdd(&counters[5], cB);
  __syncthreads();
  for (uint32_t j = t; j < cF; j += 256) {
    uint32_t p = oF + j;
    if (p < FILT_CAP) listF[p] = bufF[j];
  }
  for (uint32_t j = t; j < cB; j += 256) {
    uint32_t p = oB + j;
    if (p < FILT_CAP) listB[p] = bufB[j];
  }
}

// exact k-smallest among filtered list (all keys < T): 256-bin hist + scan + in-bin rank.
__device__ __forceinline__ void do_select(const uint64_t* list, uint32_t Mf, uint32_t k,
                                          uint32_t T, float* LBL, uint32_t* h,
                                          uint32_t* c0, uint32_t* c1, uint64_t* sub,
                                          uint32_t* scal) {
  const int t = threadIdx.x;
  if (Mf <= k) return;  // keep all (uniform)
  int bl = (T > 1u) ? (32 - __clz(T - 1u)) : 0;
  int shift = bl > 8 ? bl - 8 : 0;
  h[t] = 0u;
  if (t == 0) { scal[0] = 0u; scal[1] = 0u; scal[2] = 0u; }
  __syncthreads();
  for (uint32_t j = t; j < Mf; j += 256)
    atomicAdd(&h[((uint32_t)(list[j] >> 32)) >> shift], 1u);
  __syncthreads();
  c0[t] = h[t];
  __syncthreads();
  uint32_t* s = c0;
  uint32_t* d = c1;
  for (int dd = 1; dd < 256; dd <<= 1) {
    uint32_t v = s[t];
    if (t >= dd) v += s[t - dd];
    d[t] = v;
    __syncthreads();
    uint32_t* tmp = s; s = d; d = tmp;
  }
  uint32_t inc = s[t];
  uint32_t exc = inc - h[t];
  if (exc < k && inc >= k) { scal[1] = (uint32_t)t; scal[2] = k - exc; }
  __syncthreads();
  const uint32_t binb = scal[1], rneed = scal[2];
  for (uint32_t j = t; j < Mf; j += 256) {
    uint64_t key = list[j];
    uint32_t bin = ((uint32_t)(key >> 32)) >> shift;
    if (bin > binb) {
      LBL[(uint32_t)key] = -1.0f;
    } else if (bin == binb) {
      uint32_t p = atomicAdd(&scal[0], 1u);
      if (p < SUB_CAP) sub[p] = key;
    }
  }
  __syncthreads();
  uint32_t c = scal[0] < SUB_CAP ? scal[0] : SUB_CAP;
  for (uint32_t s2 = t; s2 < c; s2 += 256) {
    uint64_t key = sub[s2];
    uint32_t rank = 0u;
    for (uint32_t j = 0; j < c; ++j) rank += (sub[j] < key) ? 1u : 0u;
    if (rank >= rneed) LBL[(uint32_t)key] = -1.0f;
  }
  __syncthreads();
}

__global__ void __launch_bounds__(256)
k_sel(float* __restrict__ LBL, const uint64_t* __restrict__ listF,
      const uint64_t* __restrict__ listB, uint32_t* __restrict__ counters) {
  __shared__ uint32_t h[256], c0[256], c1[256];
  __shared__ uint64_t sub[SUB_CAP];
  __shared__ uint32_t scal[4];
  if (counters[8]) {
    uint32_t Mf = counters[4];
    if (Mf > FILT_CAP) Mf = FILT_CAP;
    do_select(listF, Mf, 128u, counters[10], LBL, h, c0, c1, sub, scal);
  }
  if (counters[9]) {
    uint32_t Mf = counters[5];
    if (Mf > FILT_CAP) Mf = FILT_CAP;
    do_select(listB, Mf, counters[12], counters[11], LBL, h, c0, c1, sub, scal);
  }
}

extern "C" void kernel_launch(void* const* d_in, const int* in_sizes, int n_in,
                              void* d_out, int out_size, void* d_ws, size_t ws_size,
                              hipStream_t stream) {
  (void)n_in; (void)out_size; (void)ws_size;
  const int N = in_sizes[0] / 4;  // 262144 anchors (multiple of 256)
  const int R = in_sizes[2] / 4;  // 100 gt boxes
  const int NB = N / 256;
  const float4* anc = (const float4*)d_in[0];
  const float* img = (const float*)d_in[1];
  const float4* gtb = (const float4*)d_in[2];
  float* LBL = (float*)d_out;
  float4* TGT = (float4*)((float*)d_out + N);

  uint8_t* ws = (uint8_t*)d_ws;
  uint32_t* counters = (uint32_t*)ws;                  // 16 u32 @ 0
  uint32_t* gmaxu = (uint32_t*)(ws + 512);             // 128 u32 @ 512
  uint32_t* pmeta = (uint32_t*)(ws + 1024);            // NB u32 @ 1024
  uint32_t* pmax = (uint32_t*)(ws + 8192);             // NB*R u32 (~410 KB)
  size_t off = 8192 + (size_t)NB * R * 4;
  off = (off + 7) & ~(size_t)7;
  uint64_t* candList = (uint64_t*)(ws + off);
  uint64_t* listF = (uint64_t*)(ws + off + CAND_CAP * 8);
  uint64_t* listB = (uint64_t*)(ws + off + CAND_CAP * 8 + FILT_CAP * 8);

  // Partitionable jax.random.split(key(42), 3): key_j = threefry((0,42),(0,j))
  uint32_t k1a, k1b, k2a, k2b, k3a, k3b;
  tf2x32(0u, 42u, 0u, 0u, k1a, k1b);
  tf2x32(0u, 42u, 0u, 1u, k2a, k2b);
  tf2x32(0u, 42u, 0u, 2u, k3a, k3b);

  hipMemsetAsync(ws, 0, 1024, stream);  // counters + gmaxu (init 0 = fmap floor)
  k_main<<<NB, 256, 0, stream>>>(anc, img, gtb, N, R, pmax, gmaxu, LBL, TGT, pmeta);
  k_cand<<<NB, 256, 0, stream>>>(anc, img, gtb, N, R, pmax, gmaxu, candList, counters,
                                 k1a, k1b);
  k_meta<<<1, 256, 0, stream>>>(candList, counters, LBL, pmeta, NB, R);
  k_gather<<<NB, 256, 0, stream>>>(LBL, N, listF, listB, counters, k2a, k2b, k3a, k3b);
  k_sel<<<1, 256, 0, stream>>>(LBL, listF, listB, counters);
}